// Round 10
// baseline (3062.512 us; speedup 1.0000x reference)
//
#include <hip/hip_runtime.h>

// ---------------------------------------------------------------------------
// multiStepModel: LSTM encoder (T=365) -> relu -> constant-input LSTM decoder
// (90 steps) -> relu -> FC.  Persistent cooperative kernel, 1 WG/CU.
// R10: h state exchanged in MFMA *fragment layout* (g_hf[buf][gb][bh][kb][cc]
// [bt][j], packed f16 hi|lo u32) so consumers load the B-operand DIRECTLY
// from LLC into MFMA registers with fully-coalesced 2KB/wave reads (fixes
// R6's scatter), pipelined in 4-kb chunks under the MFMA loop.  Eliminates
// the LDS commit (128 ds_write/thread) and all B-side ds_read_b128 -> ~60%
// less LDS-pipe serialization.  W tiles stay LDS-resident; R7's proven
// single-wave poll + per-WG flag publish; register LSTM cell; split-f16
// 3-term MFMA (fp32-class accuracy).
// ---------------------------------------------------------------------------

namespace {
constexpr int B = 128, T = 365, IN = 64, COV = 256, H = 512, OUTL = 90;
constexpr int GB = 4;            // batch groups (independent barrier quorums)
constexpr int GJ = 64;           // hidden groups
constexpr int NWG = GB * GJ;     // 256 workgroups, 1/CU
constexpr int NT = 256;          // threads per WG (4 waves)
constexpr int BS = B / GB;       // 32 batch rows per WG
constexpr int HU = H / GJ;       // 8 hidden units per WG
constexpr int NR = 4 * HU;       // 32 gate rows per WG (reordered unit*4+gate)
constexpr int NSLOT_H = 64;      // W tile: 512/8 16B slots (h part of K)
constexpr int NSLOT = 72;        // + 64/8 slots (x part)
}

using ull = unsigned long long;
typedef __attribute__((ext_vector_type(8))) short short8;
typedef __attribute__((ext_vector_type(8))) _Float16 half8;
typedef __attribute__((ext_vector_type(4))) float f32x4;

// Fragment-layout packed-f16 hidden state: [buf][gb][bh][kb][cc][bt][j].
// unit u -> kb=u>>5, cc=(u>>3)&3, j=u&7 ; batch b -> bh=b>>4, bt=b&15.
__device__ unsigned int g_hf[2][GB][2][16][4][16][8];   // 512 KB, LLC-resident
__device__ float g_part[OUTL][GJ][B];                   // FC partials
__device__ __align__(256) int g_flag[GB][64];           // per-WG monotonic flags

__device__ __forceinline__ float sigfast(float x) {
  return __builtin_amdgcn_rcpf(1.0f + __expf(-x));
}
__device__ __forceinline__ float tanhfast(float x) {
  return 1.0f - 2.0f * __builtin_amdgcn_rcpf(__expf(2.0f * x) + 1.0f);
}

__device__ __forceinline__ float4 fma4(float4 a, float4 b, float4 c) {
  c.x = fmaf(a.x, b.x, c.x); c.y = fmaf(a.y, b.y, c.y);
  c.z = fmaf(a.z, b.z, c.z); c.w = fmaf(a.w, b.w, c.w);
  return c;
}
__device__ __forceinline__ float hsum4(float4 a) { return (a.x + a.y) + (a.z + a.w); }

__device__ __forceinline__ unsigned int pack_split(float v) {
  _Float16 hi = (_Float16)v;
  _Float16 lo = (_Float16)(v - (float)hi);
  return ((unsigned int)__builtin_bit_cast(unsigned short, hi) << 16) |
         (unsigned int)__builtin_bit_cast(unsigned short, lo);
}
__device__ __forceinline__ float unpack_split(unsigned int u) {
  _Float16 hi = __builtin_bit_cast(_Float16, (unsigned short)(u >> 16));
  _Float16 lo = __builtin_bit_cast(_Float16, (unsigned short)(u & 0xFFFFu));
  return (float)hi + (float)lo;
}

__global__ void __launch_bounds__(256) k_init() {
  int t = threadIdx.x;
  if (t < GB * 64) g_flag[t >> 6][t & 63] = 0;
}

__global__ void __launch_bounds__(NT, 1) k_lstm(
    const float* __restrict__ input, const float* __restrict__ covar,
    const float* __restrict__ W_ih1, const float* __restrict__ W_hh1,
    const float* __restrict__ b1,    const float* __restrict__ W_ih2,
    const float* __restrict__ W_hh2, const float* __restrict__ b2,
    const float* __restrict__ W_fc) {
  // W tiles (row r = unit*4 + gate, i,f,g,o).  Slot s of row r at s ^ (r&7).
  __shared__ __align__(16) short wH[NR][NSLOT * 8];   // W hi   36.9 KB
  __shared__ __align__(16) short wL[NR][NSLOT * 8];   // W lo   36.9 KB
  __shared__ __align__(16) short xbH[BS][8 * 8];      // x_t hi  4 KB
  __shared__ __align__(16) short xbL[BS][8 * 8];      // x_t lo  4 KB
  __shared__ float pb_lds[NR][33];                    // covproj+b1 / proj2
  __shared__ float aux[4][16];                        // decoder FC combine

  const int tid = threadIdx.x;
  const int gb  = blockIdx.x & (GB - 1);
  const int gj  = blockIdx.x >> 2;
  const int bg0 = gb * BS;
  const int j0  = gj * HU;

  const int lane  = tid & 63;
  const int wv    = tid >> 6;
  const int rows0 = (wv >> 1) * 16;        // gate-row tile
  const int cols0 = (wv & 1) * 16;         // batch tile
  const int ra    = rows0 + (lane & 15);   // A row
  const int b_l   = cols0 + (lane & 15);   // B row == D col == local batch
  const int cc    = lane >> 4;             // k-chunk / gate-quad 0..3
  const int x7    = lane & 7;              // XOR swizzle key
  const int u_l   = (wv >> 1) * 4 + cc;    // this lane's local unit 0..7

  const int bl = tid >> 3;                 // x staging row 0..31
  const int sg = tid & 7;                  // x staging phase 0..7
  const int bt = tid & 15;                 // fp32 helper mapping
  const int rt = tid >> 4;

  // ---- R7-proven barrier: one wave polls all 64 member flags, then
  // __syncthreads releases the WG; publish = one relaxed AGENT store.
  auto poll64 = [&](int nb) {
    if (tid < 64) {
      while (__hip_atomic_load(&g_flag[gb][tid], __ATOMIC_RELAXED,
                               __HIP_MEMORY_SCOPE_AGENT) < nb)
        __builtin_amdgcn_s_sleep(1);
    }
  };
  auto publish = [&](int nb) {
    if (tid == 0)
      __hip_atomic_store(&g_flag[gb][gj], nb, __ATOMIC_RELAXED,
                         __HIP_MEMORY_SCOPE_AGENT);
  };

  // ---- split one 8-float slot into f16 hi/lo W tiles (XOR-swizzled) ----
  auto put_w = [&](int r, int s, const float* src) {
    float4 p0 = ((const float4*)src)[0], p1 = ((const float4*)src)[1];
    float f[8] = {p0.x, p0.y, p0.z, p0.w, p1.x, p1.y, p1.z, p1.w};
    short8 hi, lo;
#pragma unroll
    for (int j = 0; j < 8; ++j) {
      _Float16 h_ = (_Float16)f[j];
      hi[j] = __builtin_bit_cast(short, h_);
      lo[j] = __builtin_bit_cast(short, (_Float16)(f[j] - (float)h_));
    }
    const int s2 = s ^ (r & 7);
    *(short8*)&wH[r][s2 * 8] = hi;
    *(short8*)&wL[r][s2 * 8] = lo;
  };

  auto wrow = [&](int r) { return (r & 3) * H + j0 + (r >> 2); };

  auto stage_w_hh = [&](const float* Whh) {
    for (int idx = tid; idx < NR * NSLOT_H; idx += NT) {
      const int r = idx >> 6, s = idx & 63;
      put_w(r, s, Whh + (size_t)wrow(r) * H + s * 8);
    }
  };

  // x prefetch (regs) and stage (LDS slot sg of row bl)
  auto load_x_regs = [&](int tn, float4& p0, float4& p1) {
    const float* src = input + ((size_t)(bg0 + bl) * T + tn) * IN + sg * 8;
    p0 = ((const float4*)src)[0];
    p1 = ((const float4*)src)[1];
  };
  auto stage_x_regs = [&](float4 p0, float4 p1) {
    float f[8] = {p0.x, p0.y, p0.z, p0.w, p1.x, p1.y, p1.z, p1.w};
    short8 hi, lo;
#pragma unroll
    for (int j = 0; j < 8; ++j) {
      _Float16 h_ = (_Float16)f[j];
      hi[j] = __builtin_bit_cast(short, h_);
      lo[j] = __builtin_bit_cast(short, (_Float16)(f[j] - (float)h_));
    }
    const int s2 = sg ^ (bl & 7);
    *(short8*)&xbH[bl][s2 * 8] = hi;
    *(short8*)&xbL[bl][s2 * 8] = lo;
  };

  // W fragment read (A operand), kbi in [0,18): 0..15 = h, 16..17 = x
  auto rd_w = [&](int kbi, half8& ah, half8& al) {
    const int s2 = (kbi * 4 + cc) ^ x7;
    ah = __builtin_bit_cast(half8, *(const short8*)&wH[ra][s2 * 8]);
    al = __builtin_bit_cast(half8, *(const short8*)&wL[ra][s2 * 8]);
  };

  // x-part MFMA (B from the small LDS x tile)
  auto mfma_x = [&](f32x4& aA, f32x4& aB, f32x4& aC) {
#pragma unroll
    for (int xk = 0; xk < 2; ++xk) {
      const int sx = (xk * 4 + cc) ^ x7;
      const half8 bh8 = __builtin_bit_cast(half8, *(const short8*)&xbH[b_l][sx * 8]);
      const half8 bo8 = __builtin_bit_cast(half8, *(const short8*)&xbL[b_l][sx * 8]);
      half8 ah, al;
      rd_w(16 + xk, ah, al);
      aA = __builtin_amdgcn_mfma_f32_16x16x32_f16(ah, bh8, aA, 0, 0, 0);
      aB = __builtin_amdgcn_mfma_f32_16x16x32_f16(ah, bo8, aB, 0, 0, 0);
      aC = __builtin_amdgcn_mfma_f32_16x16x32_f16(al, bh8, aC, 0, 0, 0);
    }
  };

  // ---- fragment-direct B loads: chunk of 4 kb -> 16 ull (32B/lane/kb,
  // 2KB contiguous per wave per kb).  hb = base of [16][4][16][8] region.
  auto load_chunk = [&](const ull* hb, int ch, ull (&bb)[16]) {
#pragma unroll
    for (int k2 = 0; k2 < 4; ++k2) {
      const ull* p = hb + ((ch * 4 + k2) * 4 + cc) * 64 + (lane & 15) * 4;
#pragma unroll
      for (int q = 0; q < 4; ++q)
        bb[k2 * 4 + q] = __hip_atomic_load(p + q, __ATOMIC_RELAXED,
                                           __HIP_MEMORY_SCOPE_AGENT);
    }
  };
  auto mfma_chunk = [&](ull (&bb)[16], int ch, f32x4& aA, f32x4& aB, f32x4& aC) {
#pragma unroll
    for (int k2 = 0; k2 < 4; ++k2) {
      half8 bh8, bo8;
#pragma unroll
      for (int q = 0; q < 4; ++q) {
        const ull v = bb[k2 * 4 + q];
        const unsigned u0 = (unsigned)v, u1 = (unsigned)(v >> 32);
        bh8[2 * q]     = __builtin_bit_cast(_Float16, (unsigned short)(u0 >> 16));
        bo8[2 * q]     = __builtin_bit_cast(_Float16, (unsigned short)(u0 & 0xFFFFu));
        bh8[2 * q + 1] = __builtin_bit_cast(_Float16, (unsigned short)(u1 >> 16));
        bo8[2 * q + 1] = __builtin_bit_cast(_Float16, (unsigned short)(u1 & 0xFFFFu));
      }
      half8 ah, al;
      rd_w(ch * 4 + k2, ah, al);
      aA = __builtin_amdgcn_mfma_f32_16x16x32_f16(ah, bh8, aA, 0, 0, 0);
      aB = __builtin_amdgcn_mfma_f32_16x16x32_f16(ah, bo8, aB, 0, 0, 0);
      aC = __builtin_amdgcn_mfma_f32_16x16x32_f16(al, bh8, aC, 0, 0, 0);
    }
  };
  // Full h GEMM: depth-2 chunk pipeline (loads fly under MFMA + x-part).
  auto gemm_h = [&](const ull* hb, f32x4& aA, f32x4& aB, f32x4& aC, bool withx) {
    ull bb0[16], bb1[16];
    load_chunk(hb, 0, bb0);
    load_chunk(hb, 1, bb1);
    if (withx) mfma_x(aA, aB, aC);
    mfma_chunk(bb0, 0, aA, aB, aC);
    load_chunk(hb, 2, bb0);
    mfma_chunk(bb1, 1, aA, aB, aC);
    load_chunk(hb, 3, bb1);
    mfma_chunk(bb0, 2, aA, aB, aC);
    mfma_chunk(bb1, 3, aA, aB, aC);
  };

  // h' store to fragment position (one u32 per thread)
  auto store_h = [&](int par, float hv) {
    const int u = j0 + u_l;                        // global unit
    __hip_atomic_store(
        &g_hf[par][gb][b_l >> 4][u >> 5][(u >> 3) & 3][b_l & 15][u & 7],
        pack_split(hv), __ATOMIC_RELAXED, __HIP_MEMORY_SCOPE_AGENT);
  };

  // ======================= one-time setup =======================
  stage_w_hh(W_hh1);
  for (int idx = tid; idx < NR * 8; idx += NT) {   // x cols of W_ih1
    const int r = idx >> 3;
    put_w(r, NSLOT_H + (idx & 7),
          W_ih1 + (size_t)wrow(r) * (IN + COV) + (idx & 7) * 8);
  }
  {  // covariate projection + b1 -> pb_lds (fp32, once)
    const int r0 = rt, r1 = rt + 16;
    const int row0 = wrow(r0), row1 = wrow(r1);
    const float4* c0 = (const float4*)(covar + (size_t)(bg0 + bt) * COV);
    const float4* c1 = (const float4*)(covar + (size_t)(bg0 + bt + 16) * COV);
    const float4* w0 = (const float4*)(W_ih1 + (size_t)row0 * (IN + COV) + IN);
    const float4* w1 = (const float4*)(W_ih1 + (size_t)row1 * (IN + COV) + IN);
    float4 a00 = {0, 0, 0, 0}, a01 = a00, a10 = a00, a11 = a00;
    for (int k = 0; k < COV / 4; ++k) {
      float4 va = c0[k], vb = c1[k], wa = w0[k], wb = w1[k];
      a00 = fma4(va, wa, a00); a01 = fma4(va, wb, a01);
      a10 = fma4(vb, wa, a10); a11 = fma4(vb, wb, a11);
    }
    pb_lds[r0][bt]      = hsum4(a00) + b1[row0];
    pb_lds[r1][bt]      = hsum4(a01) + b1[row1];
    pb_lds[r0][bt + 16] = hsum4(a10) + b1[row0];
    pb_lds[r1][bt + 16] = hsum4(a11) + b1[row1];
  }
  {  // stage x_0
    float4 p0, p1;
    load_x_regs(0, p0, p1);
    stage_x_regs(p0, p1);
  }
  __syncthreads();   // wH/wL + pb_lds + x_0 ready

  float pb4[4];
#pragma unroll
  for (int q = 0; q < 4; ++q) pb4[q] = pb_lds[rows0 + cc * 4 + q][b_l];

  float c_state = 0.0f;

  auto cellp = [&](const f32x4& acc) -> float {
    const float gi = acc[0] + pb4[0];
    const float gf = acc[1] + pb4[1];
    const float gg = acc[2] + pb4[2];
    const float go = acc[3] + pb4[3];
    c_state = sigfast(gf) * c_state + sigfast(gi) * tanhfast(gg);
    return sigfast(go) * tanhfast(c_state);
  };

  // =================== encoder: 365 steps ===================
  for (int t = 0; t < T; ++t) {
    if (t > 0) poll64(t);
    float4 xp0, xp1;
    const bool havex = (t + 1 < T);
    if (havex) load_x_regs(t + 1, xp0, xp1);   // overlaps compute below
    __syncthreads();                           // sync1: flags verified; x ready
    f32x4 aA = {0.f, 0.f, 0.f, 0.f}, aB = aA, aC = aA;
    if (t > 0) {
      const ull* hb = (const ull*)&g_hf[t & 1][gb][cols0 >> 4][0][0][0][0];
      gemm_h(hb, aA, aB, aC, true);
    } else {
      mfma_x(aA, aB, aC);
    }
    f32x4 acc;
#pragma unroll
    for (int q = 0; q < 4; ++q) acc[q] = aA[q] + aB[q] + aC[q];
    float hv = cellp(acc);
    if (t == T - 1) hv = fmaxf(hv, 0.0f);      // relu(h_enc)
    store_h((t + 1) & 1, hv);
    __syncthreads();                           // sync2: stores+reads drained
    publish(t + 1);
    if (havex) stage_x_regs(xp0, xp1);         // read next iter after sync1
  }

  // ====== transition: proj2 = [relu(h_enc),covar] @ W_ih2^T + b2 (fp32) ======
  poll64(T);
  __syncthreads();              // all h_enc producers done (all 64 verified)
  {
    const int b0 = bt, b1v = bt + 16;
    const int r0 = rt, r1 = rt + 16;
    const int row0 = wrow(r0), row1 = wrow(r1);
    const float* w0 = W_ih2 + (size_t)row0 * (H + COV);
    const float* w1 = W_ih2 + (size_t)row1 * (H + COV);
    const ull* hb = (const ull*)&g_hf[1][gb][0][0][0][0][0];
    float a00 = 0.f, a01 = 0.f, a10 = 0.f, a11 = 0.f;
    for (int mm = 0; mm < H / 2; ++mm) {   // unit pair u=2mm, 2mm+1
      const int u = 2 * mm;
      const int kb = u >> 5, c3 = (u >> 3) & 3, jh = (u & 7) >> 1;
      const int o0 = ((((b0 >> 4) * 16 + kb) * 4 + c3) * 16 + (b0 & 15)) * 4 + jh;
      const int o1 = ((((b1v >> 4) * 16 + kb) * 4 + c3) * 16 + (b1v & 15)) * 4 + jh;
      const ull v0 = __hip_atomic_load(hb + o0, __ATOMIC_RELAXED,
                                       __HIP_MEMORY_SCOPE_AGENT);
      const ull v1 = __hip_atomic_load(hb + o1, __ATOMIC_RELAXED,
                                       __HIP_MEMORY_SCOPE_AGENT);
      const float h00 = unpack_split((unsigned)v0);
      const float h01 = unpack_split((unsigned)(v0 >> 32));
      const float h10 = unpack_split((unsigned)v1);
      const float h11 = unpack_split((unsigned)(v1 >> 32));
      const float wa0 = w0[u], wa1 = w0[u + 1];
      const float wb0 = w1[u], wb1 = w1[u + 1];
      a00 += h00 * wa0 + h01 * wa1;  a01 += h00 * wb0 + h01 * wb1;
      a10 += h10 * wa0 + h11 * wa1;  a11 += h10 * wb0 + h11 * wb1;
    }
    {  // covar part (fp32, cache-hot)
      const float4* c0 = (const float4*)(covar + (size_t)(bg0 + b0) * COV);
      const float4* c1 = (const float4*)(covar + (size_t)(bg0 + b1v) * COV);
      const float4* W0 = (const float4*)w0;
      const float4* W1 = (const float4*)w1;
      float4 s00 = {0, 0, 0, 0}, s01 = s00, s10 = s00, s11 = s00;
      for (int k = 0; k < COV / 4; ++k) {
        float4 ha = c0[k], hb2 = c1[k], wa = W0[H / 4 + k], wb = W1[H / 4 + k];
        s00 = fma4(ha, wa, s00); s01 = fma4(ha, wb, s01);
        s10 = fma4(hb2, wa, s10); s11 = fma4(hb2, wb, s11);
      }
      a00 += hsum4(s00); a01 += hsum4(s01);
      a10 += hsum4(s10); a11 += hsum4(s11);
    }
    pb_lds[r0][b0]  = a00 + b2[row0];
    pb_lds[r1][b0]  = a01 + b2[row1];
    pb_lds[r0][b1v] = a10 + b2[row0];
    pb_lds[r1][b1v] = a11 + b2[row1];
  }
  stage_w_hh(W_hh2);            // decoder recurrent weights over encoder ones
  __syncthreads();              // drains g_hf reads + publishes LDS
  publish(T + 1);               // "done reading h_enc buffer"
#pragma unroll
  for (int q = 0; q < 4; ++q) pb4[q] = pb_lds[rows0 + cc * 4 + q][b_l];
  const float wfc = W_fc[j0 + u_l];
  c_state = 0.0f;

  // =================== decoder: 90 steps ===================
  for (int ot = 0; ot < OUTL; ++ot) {
    poll64(T + 1 + ot);         // ot=0: WAR guard for h_enc buffer reuse
    __syncthreads();            // sync1
    f32x4 aA = {0.f, 0.f, 0.f, 0.f}, aB = aA, aC = aA;
    if (ot > 0) {
      const ull* hb = (const ull*)&g_hf[ot & 1][gb][cols0 >> 4][0][0][0][0];
      gemm_h(hb, aA, aB, aC, false);
    }
    f32x4 acc;
#pragma unroll
    for (int q = 0; q < 4; ++q) acc[q] = aA[q] + aB[q] + aC[q];
    const float hv = cellp(acc);             // ot==0: gates = proj2 only
    store_h((ot + 1) & 1, hv);
    // FC partial: relu(hv)*wfc summed over this WG's 8 units per batch row
    float fcv = fmaxf(hv, 0.0f) * wfc;
    fcv += __shfl_xor(fcv, 16);
    fcv += __shfl_xor(fcv, 32);              // sum over the 4 unit-lanes
    if (lane < 16) aux[wv][lane] = fcv;
    __syncthreads();            // sync2: h' stores + aux drained
    publish(T + 2 + ot);
    if (tid < 32)               // off the critical path
      g_part[ot][gj][bg0 + tid] =
          aux[tid >> 4][tid & 15] + aux[(tid >> 4) + 2][tid & 15];
  }
}

__global__ void __launch_bounds__(256) k_reduce(const float* __restrict__ b_fc,
                                                float* __restrict__ out) {
  int id = blockIdx.x * 256 + threadIdx.x;
  if (id >= B * OUTL) return;
  int b = id / OUTL, ot = id - b * OUTL;
  float s = b_fc[0];
#pragma unroll 8
  for (int g = 0; g < GJ; ++g) s += g_part[ot][g][b];
  out[id] = s;   // out[b][ot], row-major == id
}

extern "C" void kernel_launch(void* const* d_in, const int* in_sizes, int n_in,
                              void* d_out, int out_size, void* d_ws, size_t ws_size,
                              hipStream_t stream) {
  (void)in_sizes; (void)n_in; (void)d_ws; (void)ws_size; (void)out_size;
  const float* input = (const float*)d_in[0];
  const float* covar = (const float*)d_in[1];
  const float* W_ih1 = (const float*)d_in[2];
  const float* W_hh1 = (const float*)d_in[3];
  const float* b1    = (const float*)d_in[4];
  const float* W_ih2 = (const float*)d_in[5];
  const float* W_hh2 = (const float*)d_in[6];
  const float* b2    = (const float*)d_in[7];
  const float* W_fc  = (const float*)d_in[8];
  const float* b_fc  = (const float*)d_in[9];

  k_init<<<dim3(1), dim3(256), 0, stream>>>();
  k_lstm<<<dim3(NWG), dim3(NT), 0, stream>>>(input, covar, W_ih1, W_hh1, b1,
                                             W_ih2, W_hh2, b2, W_fc);
  k_reduce<<<dim3((B * OUTL + 255) / 256), dim3(256), 0, stream>>>(
      b_fc, (float*)d_out);
}

// Round 11
// 2155.843 us; speedup vs baseline: 1.4206x; 1.4206x over previous
//
#include <hip/hip_runtime.h>

// ---------------------------------------------------------------------------
// multiStepModel: LSTM encoder (T=365) -> relu -> constant-input LSTM decoder
// (90 steps) -> relu -> FC.  Persistent cooperative kernel, 1 WG/CU.
// R11 = R7 (best: dense-coalesced LLC h staging -> LDS -> split-f16 3-term
// MFMA, register cell, single-wave poll + per-WG relaxed-AGENT flag publish)
// + three individually-proven micro-wins:
//   (a) fast exp/rcp transcendentals (R8, bit-identical absmax),
//   (b) h-load / commit split with x-part MFMA overlapping the LLC flight
//       (R5's pattern; commit touches slots 0..63, x-MFMA reads 64..71),
//   (c) decoder g_part store inside the barrier wait (R8).
// ---------------------------------------------------------------------------

namespace {
constexpr int B = 128, T = 365, IN = 64, COV = 256, H = 512, OUTL = 90;
constexpr int GB = 4;            // batch groups (independent barrier quorums)
constexpr int GJ = 64;           // hidden groups
constexpr int NWG = GB * GJ;     // 256 workgroups, 1/CU
constexpr int NT = 256;          // threads per WG (4 waves)
constexpr int BS = B / GB;       // 32 batch rows per WG
constexpr int HU = H / GJ;       // 8 hidden units per WG
constexpr int NR = 4 * HU;       // 32 gate rows per WG (reordered unit*4+gate)
constexpr int NSLOT_H = 64;      // 512/8 16B slots (h part of K)
constexpr int NSLOT = 72;        // + 64/8 slots (x part)
}

using ull = unsigned long long;
typedef __attribute__((ext_vector_type(8))) short short8;
typedef __attribute__((ext_vector_type(8))) _Float16 half8;
typedef __attribute__((ext_vector_type(4))) float f32x4;

__device__ unsigned int g_h[2][B][H];          // packed f16 (hi<<16|lo) state
__device__ float g_part[OUTL][GJ][B];          // per-hidden-group FC partials
__device__ __align__(256) int g_flag[GB][64];  // per-WG monotonic flags

__device__ __forceinline__ float sigfast(float x) {
  return __builtin_amdgcn_rcpf(1.0f + __expf(-x));   // saturates correctly
}
__device__ __forceinline__ float tanhfast(float x) {
  return 1.0f - 2.0f * __builtin_amdgcn_rcpf(__expf(2.0f * x) + 1.0f);
}

__device__ __forceinline__ float4 fma4(float4 a, float4 b, float4 c) {
  c.x = fmaf(a.x, b.x, c.x); c.y = fmaf(a.y, b.y, c.y);
  c.z = fmaf(a.z, b.z, c.z); c.w = fmaf(a.w, b.w, c.w);
  return c;
}
__device__ __forceinline__ float hsum4(float4 a) { return (a.x + a.y) + (a.z + a.w); }

__device__ __forceinline__ unsigned int pack_split(float v) {
  _Float16 hi = (_Float16)v;
  _Float16 lo = (_Float16)(v - (float)hi);
  return ((unsigned int)__builtin_bit_cast(unsigned short, hi) << 16) |
         (unsigned int)__builtin_bit_cast(unsigned short, lo);
}
__device__ __forceinline__ float unpack_split(unsigned int u) {
  _Float16 hi = __builtin_bit_cast(_Float16, (unsigned short)(u >> 16));
  _Float16 lo = __builtin_bit_cast(_Float16, (unsigned short)(u & 0xFFFFu));
  return (float)hi + (float)lo;
}

__global__ void __launch_bounds__(256) k_init() {
  int t = threadIdx.x;
  if (t < GB * 64) g_flag[t >> 6][t & 63] = 0;
}

__global__ void __launch_bounds__(NT, 1) k_lstm(
    const float* __restrict__ input, const float* __restrict__ covar,
    const float* __restrict__ W_ih1, const float* __restrict__ W_hh1,
    const float* __restrict__ b1,    const float* __restrict__ W_ih2,
    const float* __restrict__ W_hh2, const float* __restrict__ b2,
    const float* __restrict__ W_fc) {
  // Row r = unit*4 + gate (i,f,g,o).  Slot s of row r stored at s ^ (r&7).
  __shared__ __align__(16) short wH[NR][NSLOT * 8];   // W hi   36.9 KB
  __shared__ __align__(16) short wL[NR][NSLOT * 8];   // W lo   36.9 KB
  __shared__ __align__(16) short bH[BS][NSLOT * 8];   // [h;x] hi
  __shared__ __align__(16) short bL[BS][NSLOT * 8];   // [h;x] lo
  __shared__ float pb_lds[NR][33];                    // covproj+b1 / proj2
  __shared__ float aux[4][16];                        // decoder FC combine

  const int tid = threadIdx.x;
  const int gb  = blockIdx.x & (GB - 1);
  const int gj  = blockIdx.x >> 2;
  const int bg0 = gb * BS;
  const int j0  = gj * HU;

  const int lane  = tid & 63;
  const int wv    = tid >> 6;
  const int rows0 = (wv >> 1) * 16;        // gate-row tile
  const int cols0 = (wv & 1) * 16;         // batch tile
  const int ra    = rows0 + (lane & 15);   // A row
  const int b_l   = cols0 + (lane & 15);   // B row == D col == batch
  const int cc    = lane >> 4;             // k-chunk / gate-quad 0..3
  const int x7    = lane & 7;              // XOR swizzle key
  const int u_l   = (wv >> 1) * 4 + cc;    // this lane's unit 0..7

  const int bl = tid >> 3;                 // staging row 0..31
  const int sg = tid & 7;                  // staging phase 0..7
  const int bt = tid & 15;                 // fp32 helper mapping
  const int rt = tid >> 4;

  // ---- split one 8-float slot into f16 hi/lo W tiles (XOR-swizzled) ----
  auto put_w = [&](int r, int s, const float* src) {
    float4 p0 = ((const float4*)src)[0], p1 = ((const float4*)src)[1];
    float f[8] = {p0.x, p0.y, p0.z, p0.w, p1.x, p1.y, p1.z, p1.w};
    short8 hi, lo;
#pragma unroll
    for (int j = 0; j < 8; ++j) {
      _Float16 h_ = (_Float16)f[j];
      hi[j] = __builtin_bit_cast(short, h_);
      lo[j] = __builtin_bit_cast(short, (_Float16)(f[j] - (float)h_));
    }
    const int s2 = s ^ (r & 7);
    *(short8*)&wH[r][s2 * 8] = hi;
    *(short8*)&wL[r][s2 * 8] = lo;
  };

  auto wrow = [&](int r) { return (r & 3) * H + j0 + (r >> 2); };

  auto stage_w_hh = [&](const float* Whh) {
    for (int idx = tid; idx < NR * NSLOT_H; idx += NT) {
      const int r = idx >> 6, s = idx & 63;
      put_w(r, s, Whh + (size_t)wrow(r) * H + s * 8);
    }
  };

  // x staging into B slots 64..71 (slot sg of row bl)
  auto stage_x = [&](int tn) {
    const float* src = input + ((size_t)(bg0 + bl) * T + tn) * IN + sg * 8;
    float4 p0 = ((const float4*)src)[0], p1 = ((const float4*)src)[1];
    float f[8] = {p0.x, p0.y, p0.z, p0.w, p1.x, p1.y, p1.z, p1.w};
    short8 hi, lo;
#pragma unroll
    for (int j = 0; j < 8; ++j) {
      _Float16 h_ = (_Float16)f[j];
      hi[j] = __builtin_bit_cast(short, h_);
      lo[j] = __builtin_bit_cast(short, (_Float16)(f[j] - (float)h_));
    }
    const int s2 = (NSLOT_H + sg) ^ (bl & 7);
    *(short8*)&bH[bl][s2 * 8] = hi;
    *(short8*)&bL[bl][s2 * 8] = lo;
  };

  // ---- per-gb-group barrier (R7-proven).  Release: __syncthreads (drains
  // vmcnt) + one relaxed-AGENT flag store per WG.  Poll: lane i watches
  // member i.  Optional x staging / g_part store ride inside the wait.
  auto gbar = [&](int nb, bool with_x, int tn, int gp_ot) {
    __syncthreads();
    if (tid == 0)
      __hip_atomic_store(&g_flag[gb][gj], nb, __ATOMIC_RELAXED,
                         __HIP_MEMORY_SCOPE_AGENT);
    if (with_x) stage_x(tn);
    if (gp_ot >= 0 && tid < 32)   // decoder FC partial store (off crit path)
      g_part[gp_ot][gj][bg0 + tid] =
          aux[tid >> 4][tid & 15] + aux[(tid >> 4) + 2][tid & 15];
    if (tid < 64) {
      while (__hip_atomic_load(&g_flag[gb][tid], __ATOMIC_RELAXED,
                               __HIP_MEMORY_SCOPE_AGENT) < nb)
        __builtin_amdgcn_s_sleep(1);
    }
    __syncthreads();
  };

  // h staging: dense 64B-coalesced LLC loads (issue) + swizzled LDS commit
  auto load_h = [&](int par, ull (&tmp)[32]) {
    const ull* hr = (const ull*)&g_h[par][bg0 + bl][0];   // 256 ull per row
#pragma unroll
    for (int i = 0; i < 32; ++i)
      tmp[i] = __hip_atomic_load(hr + sg + 8 * i, __ATOMIC_RELAXED,
                                 __HIP_MEMORY_SCOPE_AGENT);
  };
  auto commit_h = [&](ull (&tmp)[32]) {
#pragma unroll
    for (int i = 0; i < 32; ++i) {
      const int m = sg + 8 * i;                  // ull index 0..255
      const int s2 = (m >> 2) ^ (bl & 7);        // swizzled 16B slot
      const int p = m & 3;                       // word within slot
      const unsigned u0 = (unsigned)tmp[i], u1 = (unsigned)(tmp[i] >> 32);
      ((unsigned*)&bH[bl][s2 * 8])[p] = (u0 >> 16) | (u1 & 0xFFFF0000u);
      ((unsigned*)&bL[bl][s2 * 8])[p] = (u0 & 0xFFFFu) | (u1 << 16);
    }
  };

  // One MFMA k-block (3-term split product); kb 0..15 = h, 16..17 = x
  auto mfma_kb = [&](int kb, f32x4& aA, f32x4& aB, f32x4& aC) {
    const int s2 = (kb * 4 + cc) ^ x7;
    const half8 ah = __builtin_bit_cast(half8, *(const short8*)&wH[ra][s2 * 8]);
    const half8 al = __builtin_bit_cast(half8, *(const short8*)&wL[ra][s2 * 8]);
    const half8 bh = __builtin_bit_cast(half8, *(const short8*)&bH[b_l][s2 * 8]);
    const half8 bo = __builtin_bit_cast(half8, *(const short8*)&bL[b_l][s2 * 8]);
    aA = __builtin_amdgcn_mfma_f32_16x16x32_f16(ah, bh, aA, 0, 0, 0);
    aB = __builtin_amdgcn_mfma_f32_16x16x32_f16(ah, bo, aB, 0, 0, 0);
    aC = __builtin_amdgcn_mfma_f32_16x16x32_f16(al, bh, aC, 0, 0, 0);
  };

  // ======================= one-time setup =======================
  stage_w_hh(W_hh1);
  for (int idx = tid; idx < NR * 8; idx += NT) {   // x cols of W_ih1
    const int r = idx >> 3;
    put_w(r, NSLOT_H + (idx & 7),
          W_ih1 + (size_t)wrow(r) * (IN + COV) + (idx & 7) * 8);
  }
  {  // covariate projection + b1 -> pb_lds (fp32, once)
    const int r0 = rt, r1 = rt + 16;
    const int row0 = wrow(r0), row1 = wrow(r1);
    const float4* c0 = (const float4*)(covar + (size_t)(bg0 + bt) * COV);
    const float4* c1 = (const float4*)(covar + (size_t)(bg0 + bt + 16) * COV);
    const float4* w0 = (const float4*)(W_ih1 + (size_t)row0 * (IN + COV) + IN);
    const float4* w1 = (const float4*)(W_ih1 + (size_t)row1 * (IN + COV) + IN);
    float4 a00 = {0, 0, 0, 0}, a01 = a00, a10 = a00, a11 = a00;
    for (int k = 0; k < COV / 4; ++k) {
      float4 va = c0[k], vb = c1[k], wa = w0[k], wb = w1[k];
      a00 = fma4(va, wa, a00); a01 = fma4(va, wb, a01);
      a10 = fma4(vb, wa, a10); a11 = fma4(vb, wb, a11);
    }
    pb_lds[r0][bt]      = hsum4(a00) + b1[row0];
    pb_lds[r1][bt]      = hsum4(a01) + b1[row1];
    pb_lds[r0][bt + 16] = hsum4(a10) + b1[row0];
    pb_lds[r1][bt + 16] = hsum4(a11) + b1[row1];
  }
  stage_x(0);        // x_0 into B slots 64..71
  __syncthreads();   // wH/wL + pb_lds + x_0 ready

  float pb4[4];
#pragma unroll
  for (int q = 0; q < 4; ++q) pb4[q] = pb_lds[rows0 + cc * 4 + q][b_l];

  float c_state = 0.0f;

  auto cellp = [&](const f32x4& acc) -> float {
    const float gi = acc[0] + pb4[0];
    const float gf = acc[1] + pb4[1];
    const float gg = acc[2] + pb4[2];
    const float go = acc[3] + pb4[3];
    c_state = sigfast(gf) * c_state + sigfast(gi) * tanhfast(gg);
    return sigfast(go) * tanhfast(c_state);
  };

  // =================== encoder: 365 steps ===================
  for (int t = 0; t < T; ++t) {
    ull tmp[32];
    if (t > 0) load_h(t & 1, tmp);             // issue 32 LLC loads
    f32x4 aA = {0.f, 0.f, 0.f, 0.f}, aB = aA, aC = aA;
#pragma unroll
    for (int kb = 16; kb < 18; ++kb) mfma_kb(kb, aA, aB, aC);  // x part
    if (t > 0) commit_h(tmp);                  // (overlapped load flight)
    __syncthreads();                           // B h-tile ready for all waves
    if (t > 0) {
#pragma unroll
      for (int kb = 0; kb < 16; ++kb) mfma_kb(kb, aA, aB, aC); // h part
    }
    f32x4 acc;
#pragma unroll
    for (int q = 0; q < 4; ++q) acc[q] = aA[q] + aB[q] + aC[q];
    float hv = cellp(acc);
    if (t == T - 1) hv = fmaxf(hv, 0.0f);      // relu(h_enc)
    __hip_atomic_store(&g_h[(t + 1) & 1][bg0 + b_l][j0 + u_l], pack_split(hv),
                       __ATOMIC_RELAXED, __HIP_MEMORY_SCOPE_AGENT);
    gbar(t + 1, t + 1 < T, t + 1, -1);         // stage x_{t+1} in the wait
  }

  // ====== transition: proj2 = [relu(h_enc),covar] @ W_ih2^T + b2 (fp32) ======
  {
    const int b0 = bt, b1v = bt + 16;
    const int r0 = rt, r1 = rt + 16;
    const int row0 = wrow(r0), row1 = wrow(r1);
    const float* w0 = W_ih2 + (size_t)row0 * (H + COV);
    const float* w1 = W_ih2 + (size_t)row1 * (H + COV);
    const ull* h0 = (const ull*)&g_h[1][bg0 + b0][0];
    const ull* h1 = (const ull*)&g_h[1][bg0 + b1v][0];
    float a00 = 0.f, a01 = 0.f, a10 = 0.f, a11 = 0.f;
    for (int m = 0; m < H / 2; ++m) {   // h part from packed LLC state
      const ull v0 = __hip_atomic_load(h0 + m, __ATOMIC_RELAXED,
                                       __HIP_MEMORY_SCOPE_AGENT);
      const ull v1 = __hip_atomic_load(h1 + m, __ATOMIC_RELAXED,
                                       __HIP_MEMORY_SCOPE_AGENT);
      const float h00 = unpack_split((unsigned)v0);
      const float h01 = unpack_split((unsigned)(v0 >> 32));
      const float h10 = unpack_split((unsigned)v1);
      const float h11 = unpack_split((unsigned)(v1 >> 32));
      const float wa0 = w0[2 * m], wa1 = w0[2 * m + 1];
      const float wb0 = w1[2 * m], wb1 = w1[2 * m + 1];
      a00 += h00 * wa0 + h01 * wa1;  a01 += h00 * wb0 + h01 * wb1;
      a10 += h10 * wa0 + h11 * wa1;  a11 += h10 * wb0 + h11 * wb1;
    }
    {  // covar part (fp32, cache-hot)
      const float4* c0 = (const float4*)(covar + (size_t)(bg0 + b0) * COV);
      const float4* c1 = (const float4*)(covar + (size_t)(bg0 + b1v) * COV);
      const float4* W0 = (const float4*)w0;
      const float4* W1 = (const float4*)w1;
      float4 s00 = {0, 0, 0, 0}, s01 = s00, s10 = s00, s11 = s00;
      for (int k = 0; k < COV / 4; ++k) {
        float4 ha = c0[k], hb = c1[k], wa = W0[H / 4 + k], wb = W1[H / 4 + k];
        s00 = fma4(ha, wa, s00); s01 = fma4(ha, wb, s01);
        s10 = fma4(hb, wa, s10); s11 = fma4(hb, wb, s11);
      }
      a00 += hsum4(s00); a01 += hsum4(s01);
      a10 += hsum4(s10); a11 += hsum4(s11);
    }
    pb_lds[r0][b0]  = a00 + b2[row0];
    pb_lds[r1][b0]  = a01 + b2[row1];
    pb_lds[r0][b1v] = a10 + b2[row0];
    pb_lds[r1][b1v] = a11 + b2[row1];
  }
  stage_w_hh(W_hh2);            // decoder recurrent weights over encoder ones
  c_state = 0.0f;
  gbar(T + 1, false, 0, -1);    // protects g_h[1] (read above) vs ot=0 write

#pragma unroll
  for (int q = 0; q < 4; ++q) pb4[q] = pb_lds[rows0 + cc * 4 + q][b_l];
  const float wfc = W_fc[j0 + u_l];

  // =================== decoder: 90 steps ===================
  for (int ot = 0; ot < OUTL; ++ot) {
    if (ot > 0) {
      ull tmp[32];
      load_h(ot & 1, tmp);
      commit_h(tmp);
    }
    __syncthreads();
    f32x4 aA = {0.f, 0.f, 0.f, 0.f}, aB = aA, aC = aA;
    if (ot > 0) {
#pragma unroll
      for (int kb = 0; kb < 16; ++kb) mfma_kb(kb, aA, aB, aC);
    }
    f32x4 acc;
#pragma unroll
    for (int q = 0; q < 4; ++q) acc[q] = aA[q] + aB[q] + aC[q];
    const float hv = cellp(acc);             // ot==0: gates = proj2 only
    __hip_atomic_store(&g_h[(ot + 1) & 1][bg0 + b_l][j0 + u_l], pack_split(hv),
                       __ATOMIC_RELAXED, __HIP_MEMORY_SCOPE_AGENT);
    // FC partial: relu(hv)*wfc summed over this WG's 8 units per batch row
    float fcv = fmaxf(hv, 0.0f) * wfc;
    fcv += __shfl_xor(fcv, 16);
    fcv += __shfl_xor(fcv, 32);              // sum over the 4 unit-lanes
    if (lane < 16) aux[wv][lane] = fcv;
    gbar(T + 2 + ot, false, 0, ot);          // g_part store rides the wait
  }
}

__global__ void __launch_bounds__(256) k_reduce(const float* __restrict__ b_fc,
                                                float* __restrict__ out) {
  int id = blockIdx.x * 256 + threadIdx.x;
  if (id >= B * OUTL) return;
  int b = id / OUTL, ot = id - b * OUTL;
  float s = b_fc[0];
#pragma unroll 8
  for (int g = 0; g < GJ; ++g) s += g_part[ot][g][b];
  out[id] = s;   // out[b][ot], row-major == id
}

extern "C" void kernel_launch(void* const* d_in, const int* in_sizes, int n_in,
                              void* d_out, int out_size, void* d_ws, size_t ws_size,
                              hipStream_t stream) {
  (void)in_sizes; (void)n_in; (void)d_ws; (void)ws_size; (void)out_size;
  const float* input = (const float*)d_in[0];
  const float* covar = (const float*)d_in[1];
  const float* W_ih1 = (const float*)d_in[2];
  const float* W_hh1 = (const float*)d_in[3];
  const float* b1    = (const float*)d_in[4];
  const float* W_ih2 = (const float*)d_in[5];
  const float* W_hh2 = (const float*)d_in[6];
  const float* b2    = (const float*)d_in[7];
  const float* W_fc  = (const float*)d_in[8];
  const float* b_fc  = (const float*)d_in[9];

  k_init<<<dim3(1), dim3(256), 0, stream>>>();
  k_lstm<<<dim3(NWG), dim3(NT), 0, stream>>>(input, covar, W_ih1, W_hh1, b1,
                                             W_ih2, W_hh2, b2, W_fc);
  k_reduce<<<dim3((B * OUTL + 255) / 256), dim3(256), 0, stream>>>(
      b_fc, (float*)d_out);
}

// Round 12
// 2145.100 us; speedup vs baseline: 1.4277x; 1.0050x over previous
//
#include <hip/hip_runtime.h>

// ---------------------------------------------------------------------------
// multiStepModel: LSTM encoder (T=365) -> relu -> constant-input LSTM decoder
// (90 steps) -> relu -> FC.  Persistent cooperative kernel, 1 WG/CU.
// R12 = R11 (best) + loop-invariant W A-fragments hoisted into REGISTERS
// (half8 wA/wLo[16] + x frags; restaged from W_hh2 at the transition).
// Deletes the wH/wL LDS tiles and ALL W-side ds_read_b128 from the hot loop
// (~half the LDS-pipe traffic).  Skeleton, barrier, h staging, commit, cell
// are R11 verbatim (proven).  Split-f16 3-term MFMA, fast transcendentals.
// ---------------------------------------------------------------------------

namespace {
constexpr int B = 128, T = 365, IN = 64, COV = 256, H = 512, OUTL = 90;
constexpr int GB = 4;            // batch groups (independent barrier quorums)
constexpr int GJ = 64;           // hidden groups
constexpr int NWG = GB * GJ;     // 256 workgroups, 1/CU
constexpr int NT = 256;          // threads per WG (4 waves)
constexpr int BS = B / GB;       // 32 batch rows per WG
constexpr int HU = H / GJ;       // 8 hidden units per WG
constexpr int NR = 4 * HU;       // 32 gate rows per WG (reordered unit*4+gate)
constexpr int NSLOT_H = 64;      // 512/8 16B slots (h part of K)
constexpr int NSLOT = 72;        // + 64/8 slots (x part)
}

using ull = unsigned long long;
typedef __attribute__((ext_vector_type(8))) short short8;
typedef __attribute__((ext_vector_type(8))) _Float16 half8;
typedef __attribute__((ext_vector_type(4))) float f32x4;

__device__ unsigned int g_h[2][B][H];          // packed f16 (hi<<16|lo) state
__device__ float g_part[OUTL][GJ][B];          // per-hidden-group FC partials
__device__ __align__(256) int g_flag[GB][64];  // per-WG monotonic flags

__device__ __forceinline__ float sigfast(float x) {
  return __builtin_amdgcn_rcpf(1.0f + __expf(-x));   // saturates correctly
}
__device__ __forceinline__ float tanhfast(float x) {
  return 1.0f - 2.0f * __builtin_amdgcn_rcpf(__expf(2.0f * x) + 1.0f);
}

__device__ __forceinline__ float4 fma4(float4 a, float4 b, float4 c) {
  c.x = fmaf(a.x, b.x, c.x); c.y = fmaf(a.y, b.y, c.y);
  c.z = fmaf(a.z, b.z, c.z); c.w = fmaf(a.w, b.w, c.w);
  return c;
}
__device__ __forceinline__ float hsum4(float4 a) { return (a.x + a.y) + (a.z + a.w); }

__device__ __forceinline__ unsigned int pack_split(float v) {
  _Float16 hi = (_Float16)v;
  _Float16 lo = (_Float16)(v - (float)hi);
  return ((unsigned int)__builtin_bit_cast(unsigned short, hi) << 16) |
         (unsigned int)__builtin_bit_cast(unsigned short, lo);
}
__device__ __forceinline__ float unpack_split(unsigned int u) {
  _Float16 hi = __builtin_bit_cast(_Float16, (unsigned short)(u >> 16));
  _Float16 lo = __builtin_bit_cast(_Float16, (unsigned short)(u & 0xFFFFu));
  return (float)hi + (float)lo;
}

// 8 consecutive fp32 -> f16 hi/lo fragment pair
__device__ __forceinline__ void cvt8(const float* src, half8& hi, half8& lo) {
  float4 p0 = ((const float4*)src)[0], p1 = ((const float4*)src)[1];
  float f[8] = {p0.x, p0.y, p0.z, p0.w, p1.x, p1.y, p1.z, p1.w};
#pragma unroll
  for (int j = 0; j < 8; ++j) {
    _Float16 h_ = (_Float16)f[j];
    hi[j] = h_;
    lo[j] = (_Float16)(f[j] - (float)h_);
  }
}

__global__ void __launch_bounds__(256) k_init() {
  int t = threadIdx.x;
  if (t < GB * 64) g_flag[t >> 6][t & 63] = 0;
}

__global__ void __launch_bounds__(NT, 1) k_lstm(
    const float* __restrict__ input, const float* __restrict__ covar,
    const float* __restrict__ W_ih1, const float* __restrict__ W_hh1,
    const float* __restrict__ b1,    const float* __restrict__ W_ih2,
    const float* __restrict__ W_hh2, const float* __restrict__ b2,
    const float* __restrict__ W_fc) {
  // B operand tiles only (W lives in registers).  Slot s of row r at s^(r&7).
  __shared__ __align__(16) short bH[BS][NSLOT * 8];   // [h;x] hi  36.9 KB
  __shared__ __align__(16) short bL[BS][NSLOT * 8];   // [h;x] lo  36.9 KB
  __shared__ float pb_lds[NR][33];                    // covproj+b1 / proj2
  __shared__ float aux[4][16];                        // decoder FC combine

  const int tid = threadIdx.x;
  const int gb  = blockIdx.x & (GB - 1);
  const int gj  = blockIdx.x >> 2;
  const int bg0 = gb * BS;
  const int j0  = gj * HU;

  const int lane  = tid & 63;
  const int wv    = tid >> 6;
  const int rows0 = (wv >> 1) * 16;        // gate-row tile
  const int cols0 = (wv & 1) * 16;         // batch tile
  const int ra    = rows0 + (lane & 15);   // A row (reordered gate row)
  const int b_l   = cols0 + (lane & 15);   // B row == D col == batch
  const int cc    = lane >> 4;             // k-chunk / gate-quad 0..3
  const int x7    = lane & 7;              // XOR swizzle key (== b_l&7)
  const int u_l   = (wv >> 1) * 4 + cc;    // this lane's unit 0..7

  const int bl = tid >> 3;                 // staging row 0..31
  const int sg = tid & 7;                  // staging phase 0..7
  const int bt = tid & 15;                 // fp32 helper mapping
  const int rt = tid >> 4;

  // this lane's global W row: local row ra -> gate = ra&3, unit = ra>>2
  const int growA = (ra & 3) * H + j0 + (ra >> 2);

  // ---- loop-invariant W fragments in registers ----
  half8 wA[16], wLo[16];     // h-part (K blocks 0..15)   128 VGPR
  half8 xA[2],  xLo[2];      // x-part (encoder only)      16 VGPR

  auto stage_whh_regs = [&](const float* Whh) {
    const float* base = Whh + (size_t)growA * H + cc * 8;
#pragma unroll
    for (int kb = 0; kb < 16; ++kb) cvt8(base + kb * 32, wA[kb], wLo[kb]);
  };

  // ---- R11-proven barrier.  Release: __syncthreads (drains vmcnt) + one
  // relaxed-AGENT flag store per WG.  Poll: lane i watches member i.
  // Optional x staging / g_part store ride inside the wait.
  auto stage_x = [&](int tn) {
    const float* src = input + ((size_t)(bg0 + bl) * T + tn) * IN + sg * 8;
    half8 hi, lo;
    cvt8(src, hi, lo);
    const int s2 = (NSLOT_H + sg) ^ (bl & 7);
    *(short8*)&bH[bl][s2 * 8] = __builtin_bit_cast(short8, hi);
    *(short8*)&bL[bl][s2 * 8] = __builtin_bit_cast(short8, lo);
  };
  auto gbar = [&](int nb, bool with_x, int tn, int gp_ot) {
    __syncthreads();
    if (tid == 0)
      __hip_atomic_store(&g_flag[gb][gj], nb, __ATOMIC_RELAXED,
                         __HIP_MEMORY_SCOPE_AGENT);
    if (with_x) stage_x(tn);
    if (gp_ot >= 0 && tid < 32)   // decoder FC partial store (off crit path)
      g_part[gp_ot][gj][bg0 + tid] =
          aux[tid >> 4][tid & 15] + aux[(tid >> 4) + 2][tid & 15];
    if (tid < 64) {
      while (__hip_atomic_load(&g_flag[gb][tid], __ATOMIC_RELAXED,
                               __HIP_MEMORY_SCOPE_AGENT) < nb)
        __builtin_amdgcn_s_sleep(1);
    }
    __syncthreads();
  };

  // h staging: dense 64B-coalesced LLC loads (issue) + swizzled LDS commit
  auto load_h = [&](int par, ull (&tmp)[32]) {
    const ull* hr = (const ull*)&g_h[par][bg0 + bl][0];   // 256 ull per row
#pragma unroll
    for (int i = 0; i < 32; ++i)
      tmp[i] = __hip_atomic_load(hr + sg + 8 * i, __ATOMIC_RELAXED,
                                 __HIP_MEMORY_SCOPE_AGENT);
  };
  auto commit_h = [&](ull (&tmp)[32]) {
#pragma unroll
    for (int i = 0; i < 32; ++i) {
      const int m = sg + 8 * i;                  // ull index 0..255
      const int s2 = (m >> 2) ^ (bl & 7);        // swizzled 16B slot
      const int p = m & 3;                       // word within slot
      const unsigned u0 = (unsigned)tmp[i], u1 = (unsigned)(tmp[i] >> 32);
      ((unsigned*)&bH[bl][s2 * 8])[p] = (u0 >> 16) | (u1 & 0xFFFF0000u);
      ((unsigned*)&bL[bl][s2 * 8])[p] = (u0 & 0xFFFFu) | (u1 << 16);
    }
  };

  // One MFMA k-block (3-term split product); A from registers, B from LDS.
  auto mfma_kb = [&](int kb, half8 ah, half8 al,
                     f32x4& aA, f32x4& aB, f32x4& aC) {
    const int s2 = (kb * 4 + cc) ^ x7;
    const half8 bh = __builtin_bit_cast(half8, *(const short8*)&bH[b_l][s2 * 8]);
    const half8 bo = __builtin_bit_cast(half8, *(const short8*)&bL[b_l][s2 * 8]);
    aA = __builtin_amdgcn_mfma_f32_16x16x32_f16(ah, bh, aA, 0, 0, 0);
    aB = __builtin_amdgcn_mfma_f32_16x16x32_f16(ah, bo, aB, 0, 0, 0);
    aC = __builtin_amdgcn_mfma_f32_16x16x32_f16(al, bh, aC, 0, 0, 0);
  };

  // ======================= one-time setup =======================
  stage_whh_regs(W_hh1);
  {  // x-part W fragments (first IN=64 cols of W_ih1)
    const float* base = W_ih1 + (size_t)growA * (IN + COV) + cc * 8;
#pragma unroll
    for (int xk = 0; xk < 2; ++xk) cvt8(base + xk * 32, xA[xk], xLo[xk]);
  }
  {  // covariate projection + b1 -> pb_lds (fp32, once)
    auto wrow = [&](int r) { return (r & 3) * H + j0 + (r >> 2); };
    const int r0 = rt, r1 = rt + 16;
    const int row0 = wrow(r0), row1 = wrow(r1);
    const float4* c0 = (const float4*)(covar + (size_t)(bg0 + bt) * COV);
    const float4* c1 = (const float4*)(covar + (size_t)(bg0 + bt + 16) * COV);
    const float4* w0 = (const float4*)(W_ih1 + (size_t)row0 * (IN + COV) + IN);
    const float4* w1 = (const float4*)(W_ih1 + (size_t)row1 * (IN + COV) + IN);
    float4 a00 = {0, 0, 0, 0}, a01 = a00, a10 = a00, a11 = a00;
    for (int k = 0; k < COV / 4; ++k) {
      float4 va = c0[k], vb = c1[k], wa = w0[k], wb = w1[k];
      a00 = fma4(va, wa, a00); a01 = fma4(va, wb, a01);
      a10 = fma4(vb, wa, a10); a11 = fma4(vb, wb, a11);
    }
    pb_lds[r0][bt]      = hsum4(a00) + b1[row0];
    pb_lds[r1][bt]      = hsum4(a01) + b1[row1];
    pb_lds[r0][bt + 16] = hsum4(a10) + b1[row0];
    pb_lds[r1][bt + 16] = hsum4(a11) + b1[row1];
  }
  stage_x(0);        // x_0 into B slots 64..71
  __syncthreads();   // pb_lds + x_0 ready

  float pb4[4];
#pragma unroll
  for (int q = 0; q < 4; ++q) pb4[q] = pb_lds[rows0 + cc * 4 + q][b_l];

  float c_state = 0.0f;

  auto cellp = [&](const f32x4& acc) -> float {
    const float gi = acc[0] + pb4[0];
    const float gf = acc[1] + pb4[1];
    const float gg = acc[2] + pb4[2];
    const float go = acc[3] + pb4[3];
    c_state = sigfast(gf) * c_state + sigfast(gi) * tanhfast(gg);
    return sigfast(go) * tanhfast(c_state);
  };

  // =================== encoder: 365 steps ===================
  for (int t = 0; t < T; ++t) {
    ull tmp[32];
    if (t > 0) load_h(t & 1, tmp);             // issue 32 LLC loads
    f32x4 aA = {0.f, 0.f, 0.f, 0.f}, aB = aA, aC = aA;
#pragma unroll
    for (int xk = 0; xk < 2; ++xk)             // x part (W in regs)
      mfma_kb(16 + xk, xA[xk], xLo[xk], aA, aB, aC);
    if (t > 0) commit_h(tmp);                  // (overlapped load flight)
    __syncthreads();                           // B h-tile ready for all waves
    if (t > 0) {
#pragma unroll
      for (int kb = 0; kb < 16; ++kb)
        mfma_kb(kb, wA[kb], wLo[kb], aA, aB, aC);   // h part (W in regs)
    }
    f32x4 acc;
#pragma unroll
    for (int q = 0; q < 4; ++q) acc[q] = aA[q] + aB[q] + aC[q];
    float hv = cellp(acc);
    if (t == T - 1) hv = fmaxf(hv, 0.0f);      // relu(h_enc)
    __hip_atomic_store(&g_h[(t + 1) & 1][bg0 + b_l][j0 + u_l], pack_split(hv),
                       __ATOMIC_RELAXED, __HIP_MEMORY_SCOPE_AGENT);
    gbar(t + 1, t + 1 < T, t + 1, -1);         // stage x_{t+1} in the wait
  }

  // ====== transition: proj2 = [relu(h_enc),covar] @ W_ih2^T + b2 (fp32) ======
  {
    auto wrow = [&](int r) { return (r & 3) * H + j0 + (r >> 2); };
    const int b0 = bt, b1v = bt + 16;
    const int r0 = rt, r1 = rt + 16;
    const int row0 = wrow(r0), row1 = wrow(r1);
    const float* w0 = W_ih2 + (size_t)row0 * (H + COV);
    const float* w1 = W_ih2 + (size_t)row1 * (H + COV);
    const ull* h0 = (const ull*)&g_h[1][bg0 + b0][0];
    const ull* h1 = (const ull*)&g_h[1][bg0 + b1v][0];
    float a00 = 0.f, a01 = 0.f, a10 = 0.f, a11 = 0.f;
    for (int m = 0; m < H / 2; ++m) {   // h part from packed LLC state
      const ull v0 = __hip_atomic_load(h0 + m, __ATOMIC_RELAXED,
                                       __HIP_MEMORY_SCOPE_AGENT);
      const ull v1 = __hip_atomic_load(h1 + m, __ATOMIC_RELAXED,
                                       __HIP_MEMORY_SCOPE_AGENT);
      const float h00 = unpack_split((unsigned)v0);
      const float h01 = unpack_split((unsigned)(v0 >> 32));
      const float h10 = unpack_split((unsigned)v1);
      const float h11 = unpack_split((unsigned)(v1 >> 32));
      const float wa0 = w0[2 * m], wa1 = w0[2 * m + 1];
      const float wb0 = w1[2 * m], wb1 = w1[2 * m + 1];
      a00 += h00 * wa0 + h01 * wa1;  a01 += h00 * wb0 + h01 * wb1;
      a10 += h10 * wa0 + h11 * wa1;  a11 += h10 * wb0 + h11 * wb1;
    }
    {  // covar part (fp32, cache-hot)
      const float4* c0 = (const float4*)(covar + (size_t)(bg0 + b0) * COV);
      const float4* c1 = (const float4*)(covar + (size_t)(bg0 + b1v) * COV);
      const float4* W0 = (const float4*)w0;
      const float4* W1 = (const float4*)w1;
      float4 s00 = {0, 0, 0, 0}, s01 = s00, s10 = s00, s11 = s00;
      for (int k = 0; k < COV / 4; ++k) {
        float4 ha = c0[k], hb = c1[k], wa = W0[H / 4 + k], wb = W1[H / 4 + k];
        s00 = fma4(ha, wa, s00); s01 = fma4(ha, wb, s01);
        s10 = fma4(hb, wa, s10); s11 = fma4(hb, wb, s11);
      }
      a00 += hsum4(s00); a01 += hsum4(s01);
      a10 += hsum4(s10); a11 += hsum4(s11);
    }
    pb_lds[r0][b0]  = a00 + b2[row0];
    pb_lds[r1][b0]  = a01 + b2[row1];
    pb_lds[r0][b1v] = a10 + b2[row0];
    pb_lds[r1][b1v] = a11 + b2[row1];
  }
  stage_whh_regs(W_hh2);        // decoder recurrent W -> registers
  c_state = 0.0f;
  gbar(T + 1, false, 0, -1);    // protects g_h[1] (read above) vs ot=0 write

#pragma unroll
  for (int q = 0; q < 4; ++q) pb4[q] = pb_lds[rows0 + cc * 4 + q][b_l];
  const float wfc = W_fc[j0 + u_l];

  // =================== decoder: 90 steps ===================
  for (int ot = 0; ot < OUTL; ++ot) {
    if (ot > 0) {
      ull tmp[32];
      load_h(ot & 1, tmp);
      commit_h(tmp);
    }
    __syncthreads();
    f32x4 aA = {0.f, 0.f, 0.f, 0.f}, aB = aA, aC = aA;
    if (ot > 0) {
#pragma unroll
      for (int kb = 0; kb < 16; ++kb)
        mfma_kb(kb, wA[kb], wLo[kb], aA, aB, aC);
    }
    f32x4 acc;
#pragma unroll
    for (int q = 0; q < 4; ++q) acc[q] = aA[q] + aB[q] + aC[q];
    const float hv = cellp(acc);             // ot==0: gates = proj2 only
    __hip_atomic_store(&g_h[(ot + 1) & 1][bg0 + b_l][j0 + u_l], pack_split(hv),
                       __ATOMIC_RELAXED, __HIP_MEMORY_SCOPE_AGENT);
    // FC partial: relu(hv)*wfc summed over this WG's 8 units per batch row
    float fcv = fmaxf(hv, 0.0f) * wfc;
    fcv += __shfl_xor(fcv, 16);
    fcv += __shfl_xor(fcv, 32);              // sum over the 4 unit-lanes
    if (lane < 16) aux[wv][lane] = fcv;
    gbar(T + 2 + ot, false, 0, ot);          // g_part store rides the wait
  }
}

__global__ void __launch_bounds__(256) k_reduce(const float* __restrict__ b_fc,
                                                float* __restrict__ out) {
  int id = blockIdx.x * 256 + threadIdx.x;
  if (id >= B * OUTL) return;
  int b = id / OUTL, ot = id - b * OUTL;
  float s = b_fc[0];
#pragma unroll 8
  for (int g = 0; g < GJ; ++g) s += g_part[ot][g][b];
  out[id] = s;   // out[b][ot], row-major == id
}

extern "C" void kernel_launch(void* const* d_in, const int* in_sizes, int n_in,
                              void* d_out, int out_size, void* d_ws, size_t ws_size,
                              hipStream_t stream) {
  (void)in_sizes; (void)n_in; (void)d_ws; (void)ws_size; (void)out_size;
  const float* input = (const float*)d_in[0];
  const float* covar = (const float*)d_in[1];
  const float* W_ih1 = (const float*)d_in[2];
  const float* W_hh1 = (const float*)d_in[3];
  const float* b1    = (const float*)d_in[4];
  const float* W_ih2 = (const float*)d_in[5];
  const float* W_hh2 = (const float*)d_in[6];
  const float* b2    = (const float*)d_in[7];
  const float* W_fc  = (const float*)d_in[8];
  const float* b_fc  = (const float*)d_in[9];

  k_init<<<dim3(1), dim3(256), 0, stream>>>();
  k_lstm<<<dim3(NWG), dim3(NT), 0, stream>>>(input, covar, W_ih1, W_hh1, b1,
                                             W_ih2, W_hh2, b2, W_fc);
  k_reduce<<<dim3((B * OUTL + 255) / 256), dim3(256), 0, stream>>>(
      b_fc, (float*)d_out);
}